// Round 16
// baseline (289.578 us; speedup 1.0000x reference)
//
#include <hip/hip_runtime.h>

typedef __bf16 bf16x8 __attribute__((ext_vector_type(8)));
typedef float  f32x4  __attribute__((ext_vector_type(4)));
typedef unsigned short ushort8 __attribute__((ext_vector_type(8)));

#define KDIM  4096
#define NDIM  4096
#define REDIN 2048

static __device__ __forceinline__ unsigned short f2bf(float f) {
    return __builtin_bit_cast(unsigned short, (__bf16)f);
}

typedef __attribute__((address_space(3))) void       lds_void;
typedef const __attribute__((address_space(1))) void gbl_cvoid;

static __device__ __forceinline__ void gload16(const void* g, void* l) {
    __builtin_amdgcn_global_load_lds((gbl_cvoid*)g, (lds_void*)l, 16, 0, 0);
}

// ---------------- fused prep: blocks [0,2048) convert x; [2048,3072) expand w ----------------
__global__ void prep_fused(const float* __restrict__ x, const float* __restrict__ w,
                           const int* __restrict__ rn,
                           unsigned short* __restrict__ xb, unsigned short* __restrict__ wx,
                           long n8x) {
    if (blockIdx.x < 2048) {
        long idx = (long)blockIdx.x * blockDim.x + threadIdx.x;
        long stride = (long)2048 * blockDim.x;
        for (long i = idx; i < n8x; i += stride) {
            const float4 a = ((const float4*)x)[2 * i];
            const float4 b = ((const float4*)x)[2 * i + 1];
            ushort8 s;
            s[0] = f2bf(a.x); s[1] = f2bf(a.y); s[2] = f2bf(a.z); s[3] = f2bf(a.w);
            s[4] = f2bf(b.x); s[5] = f2bf(b.y); s[6] = f2bf(b.z); s[7] = f2bf(b.w);
            ((ushort8*)xb)[i] = s;
        }
    } else {
        const int R0 = rn[0], R1 = rn[1], R2 = rn[2], R3 = rn[3];
        const long total = (long)NDIM * (KDIM / 8);
        long idx = (long)(blockIdx.x - 2048) * blockDim.x + threadIdx.x;
        long stride = (long)1024 * blockDim.x;
        for (long t = idx; t < total; t += stride) {
            const int kp = (int)(t & (KDIM / 8 - 1));
            const int n  = (int)(t >> 9);
            const int k0 = kp * 8;
            const int i  = k0 >> 5;
            const int kk0 = k0 & 31;
            const int it = i >> 1;
            const int h  = R3 + R2 * (n >> 5) + R1 * (it + 1) + R0 * ((i & 1) + 1);
            const int off = 32 - ((h << 2) & 31);
            const float* src = w + (long)n * REDIN + it * 32;
            ushort8 s;
#pragma unroll
            for (int q = 0; q < 8; ++q)
                s[q] = f2bf(src[(kk0 + q + off) & 31]);
            ((ushort8*)wx)[t] = s;
        }
    }
}

// ======== main GEMM: 256x256, BK=64, 2-buf ring, phi-region staging, depth-6 pipeline ========
// 8 waves 2Mx4N, per-wave 128x64. LDS: A[2buf][256][64]bf16 64KB + B same (row r at byte r*128
// within a 32KB buffer). Bank swizzle (proven 0-conflict): phys 16B slot = logical ^ (row&7);
// linear gload dest + inverse-swizzled global source + swizzled ds_read.
//
// phi-region definition (SINGLE-PHASE liveness — the R12/R14 race fix):
//   A-phi0 = rows {0-63, 128-191}   : read ONLY at P1 (both wave-groups' quadrant 0)
//   A-phi1 = rows {64-127, 192-255} : read ONLY at P3
//   B-phi0 = rows with (r&63)<32    : read ONLY at P1
//   B-phi1 = rows with (r&63)>=32   : read ONLY at P2
//
// Group u (tile u from buf u&1), 4 phases, 1 barrier/phase:
//   P1: read A-phi0 x8 + B-phi0 x4; stage A(u+1)phi1 [other buf]; lgkm(4); BAR; lgkm(0); MFMA(0,0)
//   P2: read B-phi1 x4; stage A(u+2)phi0 [buf u&1, dead since P1]; vmcnt(VM2); BAR; lgkm(0); MFMA(0,1)
//   P3: read A-phi1 x8; stage B(u+2)phi0 [buf u&1, dead since P1]; BAR; lgkm(0); MFMA(1,1)
//   P4: stage B(u+2)phi1 [buf u&1, dead since P2]; MFMA(1,0); vmcnt(VM1); BAR
//
// WAR audit: every same-buf stage targets a phi-region whose ONLY reads this group were
//   >=1 barrier earlier and lgkm-drained before that barrier's MFMA. A(u+1)phi1 targets the
//   other buffer (last read P3(u-1), drained before BAR(P4,u-1)). All stages barrier-separated
//   from conflicting reads (gload LDS-write lands >=500cy after issue; nearest prior read
//   drains within ~100cy of the shared barrier release — margin >400cy on the one 1-barrier edge).
// RAW gates (steady state, counts in gload pairs, oldest-first drain):
//   after Gate1(P4,u-1): 8 outstanding = {Aphi1(u)[P1,u-1], Aphi0(u+1)[P2,u-1], Bphi0(u+1)[P3,u-1],
//     Bphi1(u+1)[P4,u-1]}. P1(u)+2 ->10; Gate2 vmcnt(10)@P2 pre-BAR drains nothing yet... P2(u)+2 ->12,
//     vmcnt(10) drains Aphi1(u) (read at P3(u), 5 phases after issue) ✓; P3+2, P4+2 ->14;
//     Gate1 vmcnt(8) drains Aphi0/Bphi0/Bphi1(u+1) (read P1/P2(u+1), staged 6-7 phases earlier) ✓.
//   Induction: post-Gate1(P4,u) = {Aphi1(u+1), Aphi0(u+2), Bphi0(u+2), Bphi1(u+2)} ✓.
// Tail: group 62 stages only Aphi1(63) (VM2="8" drains Aphi1(62); VM1="2" leaves Aphi1(63));
//   group 63 stages nothing (VM2="0" drains Aphi1(63); VM1="0").

#define STAGE_A(T, PHI)                                                     \
  {                                                                         \
    char* _d = (char*)ldsA + (((T) & 1) * 32768) + ((PHI) * 8192) + tid * 16; \
    const unsigned short* _s = srcA + (size_t)((PHI) * 64) * KDIM + (size_t)(T) * 64; \
    gload16(_s, _d);                                                        \
    gload16(_s + (size_t)128 * KDIM, _d + 16384);                           \
  }

#define STAGE_B(T, PHI)                                                     \
  {                                                                         \
    char* _b = (char*)ldsB + (((T) & 1) * 32768) + ((PHI) * 4096);          \
    const size_t _ko = (size_t)((PHI) * 32) * KDIM + (size_t)(T) * 64;      \
    gload16(srcB0 + _ko, _b + boff0);                                       \
    gload16(srcB1 + _ko, _b + boff1);                                       \
  }

#define READ_A(PA, MH)                                                      \
  _Pragma("unroll")                                                         \
  for (int _kk = 0; _kk < 2; ++_kk)                                         \
    _Pragma("unroll")                                                       \
    for (int _mf = 0; _mf < 4; ++_mf)                                       \
      a_[_kk][_mf] = *(const bf16x8*)((PA) + (MH) * 8192 + _mf * 2048 + (roff ^ (_kk << 6)));

#define READ_B(PB, NH)                                                      \
  _Pragma("unroll")                                                         \
  for (int _kk = 0; _kk < 2; ++_kk)                                         \
    _Pragma("unroll")                                                       \
    for (int _nf = 0; _nf < 2; ++_nf)                                       \
      b_##NH[_kk][_nf] = *(const bf16x8*)((PB) + (NH) * 4096 + _nf * 2048 + (roff ^ (_kk << 6)));

#define MFMA_Q(MH, NH)                                                      \
  __builtin_amdgcn_s_setprio(1);                                            \
  _Pragma("unroll")                                                         \
  for (int _kk = 0; _kk < 2; ++_kk)                                         \
    _Pragma("unroll")                                                       \
    for (int _mf = 0; _mf < 4; ++_mf)                                       \
      _Pragma("unroll")                                                     \
      for (int _nf = 0; _nf < 2; ++_nf)                                     \
        acc[(MH) * 4 + _mf][(NH) * 2 + _nf] = __builtin_amdgcn_mfma_f32_16x16x32_bf16( \
            a_[_kk][_mf], b_##NH[_kk][_nf], acc[(MH) * 4 + _mf][(NH) * 2 + _nf], 0, 0, 0); \
  __builtin_amdgcn_s_setprio(0);

#define SB __builtin_amdgcn_sched_barrier(0)
#define BAR __builtin_amdgcn_s_barrier()

// STG: 2 = full stage rotation, 1 = only P1's A(u+1)phi1, 0 = none.
#define GROUP(U, BUF, STG, VM2, VM1)                                        \
  {                                                                         \
    const char* paA = ldsAc + (BUF) * 32768 + wr * 16384;                   \
    const char* pbB = ldsBc + (BUF) * 32768 + bh * 16384 + bhw;             \
    /* P1 */                                                                \
    READ_A(paA, 0)                                                          \
    READ_B(pbB, 0)                                                          \
    if ((STG) >= 1) STAGE_A((U) + 1, 1);                                    \
    asm volatile("s_waitcnt lgkmcnt(4)" ::: "memory");                      \
    SB; BAR;                                                                \
    asm volatile("s_waitcnt lgkmcnt(0)" ::: "memory");                      \
    SB;                                                                     \
    MFMA_Q(0, 0)                                                            \
    SB;                                                                     \
    /* P2 */                                                                \
    READ_B(pbB, 1)                                                          \
    if ((STG) >= 2) STAGE_A((U) + 2, 0);                                    \
    asm volatile("s_waitcnt vmcnt(" VM2 ")" ::: "memory");                  \
    SB; BAR;                                                                \
    asm volatile("s_waitcnt lgkmcnt(0)" ::: "memory");                      \
    SB;                                                                     \
    MFMA_Q(0, 1)                                                            \
    SB;                                                                     \
    /* P3 */                                                                \
    READ_A(paA, 1)                                                          \
    if ((STG) >= 2) STAGE_B((U) + 2, 0);                                    \
    SB; BAR;                                                                \
    asm volatile("s_waitcnt lgkmcnt(0)" ::: "memory");                      \
    SB;                                                                     \
    MFMA_Q(1, 1)                                                            \
    SB;                                                                     \
    /* P4 */                                                                \
    if ((STG) >= 2) STAGE_B((U) + 2, 1);                                    \
    SB;                                                                     \
    MFMA_Q(1, 0)                                                            \
    asm volatile("s_waitcnt vmcnt(" VM1 ")" ::: "memory");                  \
    SB; BAR; SB;                                                            \
  }

__global__ __launch_bounds__(512, 2)
void gemm_bt256(const unsigned short* __restrict__ A,   // bf16 [M][K]
                const unsigned short* __restrict__ B,   // bf16 [N][K]
                const float* __restrict__ bias,
                float* __restrict__ out, int M)
{
    __shared__ __align__(16) unsigned short ldsA[2 * 16384];   // 64 KB (2 x 32KB buffers)
    __shared__ __align__(16) unsigned short ldsB[2 * 16384];   // 64 KB
    const char* ldsAc = (const char*)ldsA;
    const char* ldsBc = (const char*)ldsB;

    // XCD-aware bijective swizzle (nwg = 16*(M/256), divisible by 8)
    const int nwg = gridDim.x;
    const int bid = blockIdx.x;
    int swzb = bid;
    if ((nwg & 7) == 0) {
        const int cpx = nwg >> 3;
        swzb = (bid & 7) * cpx + (bid >> 3);
    }
    const int ntn = NDIM / 256;                 // 16
    const int n0 = (swzb % ntn) * 256;
    const int m0 = (swzb / ntn) * 256;

    const int tid  = threadIdx.x;
    const int lane = tid & 63;
    const int wid  = tid >> 6;
    const int wr   = wid >> 2;                  // A half (0..1)
    const int wc   = wid & 3;                   // 0..3
    const int bh   = wc >> 1;                   // B half
    const int bhw  = (wc & 1) * 8192;           // 64-row offset within B half (bytes)
    const int lrow = lane & 15;
    const int g    = lane >> 4;                 // k sub-group 0..3

    // frag read offset: row*128B + swizzled 16B slot
    const int roff = lrow * 128 + (((g ^ (lrow & 7)) & 7) << 4);

    // A staging: linear LDS dest (tid*16B within phi-chunk), inverse-swizzled global k source
    const int srow = tid >> 3;                  // 0..63
    const int sslot = (tid & 7) ^ (srow & 7);
    const unsigned short* srcA = A + (size_t)(m0 + srow) * KDIM + 8 * sslot;

    // B staging: interleaved phi-slots. Wave w writes slots s0=wid, s1=wid+8 (1KB each).
    // slot s -> LDS byte (s>>2)*8192 + (s&3)*1024 + PHI*4096 + lane*16
    //        -> global row (s>>2)*64 + PHI*32 + (s&3)*8 + (lane>>3)
    const int s0i = wid, s1i = wid + 8;
    const int boff0 = (s0i >> 2) * 8192 + (s0i & 3) * 1024 + lane * 16;
    const int boff1 = (s1i >> 2) * 8192 + (s1i & 3) * 1024 + lane * 16;
    const int rB0 = (s0i >> 2) * 64 + (s0i & 3) * 8 + (lane >> 3);
    const int rB1 = (s1i >> 2) * 64 + (s1i & 3) * 8 + (lane >> 3);
    const int kslotB = (lane & 7) ^ (lane >> 3);   // row&7 == lane>>3 for all staged B rows
    const unsigned short* srcB0 = B + (size_t)(n0 + rB0) * KDIM + 8 * kslotB;
    const unsigned short* srcB1 = B + (size_t)(n0 + rB1) * KDIM + 8 * kslotB;

    f32x4 acc[8][4];
#pragma unroll
    for (int m = 0; m < 8; ++m)
#pragma unroll
        for (int n = 0; n < 4; ++n)
            acc[m][n] = (f32x4)(0.0f);

    bf16x8 a_[2][4], b_0[2][2], b_1[2][2];

    // ---- prologue: tile0 complete (4 pairs) + tile1 {Aphi0, Bphi0, Bphi1} (3 pairs) ----
    STAGE_A(0, 0);
    STAGE_B(0, 0);
    STAGE_B(0, 1);
    STAGE_A(0, 1);
    STAGE_A(1, 0);
    STAGE_B(1, 0);
    STAGE_B(1, 1);
    asm volatile("s_waitcnt vmcnt(6)" ::: "memory");   // tile 0 landed; 3 tile-1 pairs in flight
    SB; BAR; SB;

    // ---- main: groups 0..61 ----
    for (int u = 0; u < 62; u += 2) {
        GROUP(u,     0, 2, "10", "8");
        GROUP(u + 1, 1, 2, "10", "8");
    }
    // ---- tail ----
    GROUP(62, 0, 1, "8", "2");   // stages only Aphi1(63); gates drain progressively
    GROUP(63, 1, 0, "0", "0");   // compute-only

    // ---- epilogue ----
#pragma unroll
    for (int n = 0; n < 4; ++n) {
        const int col = n0 + wc * 64 + n * 16 + lrow;
        const float bv = bias[col];
#pragma unroll
        for (int m = 0; m < 8; ++m) {
            const size_t rbase = (size_t)(m0 + wr * 128 + m * 16 + (lane >> 4) * 4);
#pragma unroll
            for (int e = 0; e < 4; ++e)
                out[(rbase + e) * NDIM + col] = acc[m][n][e] + bv;
        }
    }
}

// ---------------- fallback (fused) for small ws ----------------
__global__ __launch_bounds__(256, 2)
void ssl_gemm_fused(const float* __restrict__ x, const float* __restrict__ w,
                    const float* __restrict__ bias, const int* __restrict__ rn,
                    float* __restrict__ out)
{
    __shared__ __align__(16) unsigned short As[128][40];
    __shared__ __align__(16) unsigned short Bs[128][40];

    const int R0 = rn[0], R1 = rn[1], R2 = rn[2], R3 = rn[3];
    const int tid = threadIdx.x;
    const int n0 = blockIdx.x * 128;
    const int m0 = blockIdx.y * 128;
    const int srow = tid >> 3;
    const int scol = (tid & 7) * 4;
    const int lane = tid & 63;
    const int wid  = tid >> 6;
    const int wr   = wid >> 1;
    const int wc   = wid & 1;
    const int lrow = lane & 15;
    const int lk   = (lane >> 4) * 8;

    f32x4 acc[4][4];
#pragma unroll
    for (int m = 0; m < 4; ++m)
#pragma unroll
        for (int n = 0; n < 4; ++n)
            acc[m][n] = (f32x4)(0.0f);

    for (int i = 0; i < KDIM / 32; ++i) {
        const int it   = i >> 1;
        const int k0   = i * 32;
#pragma unroll
        for (int p = 0; p < 4; ++p) {
            const int row = p * 32 + srow;
            const float4 v = *(const float4*)(x + (size_t)(m0 + row) * KDIM + k0 + scol);
            ushort4 s;
            s.x = f2bf(v.x); s.y = f2bf(v.y); s.z = f2bf(v.z); s.w = f2bf(v.w);
            *(ushort4*)&As[row][scol] = s;
        }
        const int hbase = R3 + R1 * (it + 1) + R0 * ((i & 1) + 1);
#pragma unroll
        for (int p = 0; p < 4; ++p) {
            const int nl = p * 32 + srow;
            const int j  = (n0 + nl) >> 5;
            const int off = 32 - (((hbase + R2 * j) << 2) & 31);
            const float4 v = *(const float4*)(w + (size_t)(n0 + nl) * REDIN + it * 32 + scol);
            Bs[nl][(scol + 0 - off) & 31] = f2bf(v.x);
            Bs[nl][(scol + 1 - off) & 31] = f2bf(v.y);
            Bs[nl][(scol + 2 - off) & 31] = f2bf(v.z);
            Bs[nl][(scol + 3 - off) & 31] = f2bf(v.w);
        }
        __syncthreads();

        bf16x8 af[4], bfr[4];
#pragma unroll
        for (int m = 0; m < 4; ++m)
            af[m] = *(const bf16x8*)&As[wr * 64 + m * 16 + lrow][lk];
#pragma unroll
        for (int n = 0; n < 4; ++n)
            bfr[n] = *(const bf16x8*)&Bs[wc * 64 + n * 16 + lrow][lk];
#pragma unroll
        for (int m = 0; m < 4; ++m)
#pragma unroll
            for (int n = 0; n < 4; ++n)
                acc[m][n] = __builtin_amdgcn_mfma_f32_16x16x32_bf16(af[m], bfr[n], acc[m][n], 0, 0, 0);
        __syncthreads();
    }

#pragma unroll
    for (int n = 0; n < 4; ++n) {
        const int col = n0 + wc * 64 + n * 16 + lrow;
        const float bv = bias[col];
#pragma unroll
        for (int m = 0; m < 4; ++m) {
            const int rbase = m0 + wr * 64 + m * 16 + (lane >> 4) * 4;
#pragma unroll
            for (int e = 0; e < 4; ++e)
                out[(size_t)(rbase + e) * NDIM + col] = acc[m][n][e] + bv;
        }
    }
}

extern "C" void kernel_launch(void* const* d_in, const int* in_sizes, int n_in,
                              void* d_out, int out_size, void* d_ws, size_t ws_size,
                              hipStream_t stream) {
    const float* x    = (const float*)d_in[0];
    const float* wgt  = (const float*)d_in[1];
    const float* bias = (const float*)d_in[2];
    const int*   rn   = (const int*)d_in[3];
    float* out = (float*)d_out;

    const int M = in_sizes[0] / KDIM;                       // 8192
    const size_t need = ((size_t)M * KDIM + (size_t)NDIM * KDIM) * sizeof(unsigned short);

    if (ws_size >= need && (M % 256) == 0) {
        unsigned short* xb = (unsigned short*)d_ws;
        unsigned short* wx = xb + (size_t)M * KDIM;

        prep_fused<<<3072, 256, 0, stream>>>(x, wgt, rn, xb, wx, (long)M * KDIM / 8);

        const int nwg = (NDIM / 256) * (M / 256);           // 512
        gemm_bt256<<<nwg, 512, 0, stream>>>(xb, wx, bias, out, M);
    } else {
        dim3 grid(NDIM / 128, M / 128);
        ssl_gemm_fused<<<grid, dim3(256), 0, stream>>>(x, wgt, bias, rn, out);
    }
}

// Round 17
// 271.836 us; speedup vs baseline: 1.0653x; 1.0653x over previous
//
#include <hip/hip_runtime.h>

typedef __bf16 bf16x8 __attribute__((ext_vector_type(8)));
typedef float  f32x4  __attribute__((ext_vector_type(4)));
typedef unsigned short ushort8 __attribute__((ext_vector_type(8)));

#define KDIM  4096
#define NDIM  4096
#define REDIN 2048

static __device__ __forceinline__ unsigned short f2bf(float f) {
    return __builtin_bit_cast(unsigned short, (__bf16)f);
}

typedef __attribute__((address_space(3))) void       lds_void;
typedef const __attribute__((address_space(1))) void gbl_cvoid;

static __device__ __forceinline__ void gload16(const void* g, void* l) {
    __builtin_amdgcn_global_load_lds((gbl_cvoid*)g, (lds_void*)l, 16, 0, 0);
}

// ---------------- fused prep: blocks [0,2048) convert x; [2048,3072) expand w ----------------
__global__ void prep_fused(const float* __restrict__ x, const float* __restrict__ w,
                           const int* __restrict__ rn,
                           unsigned short* __restrict__ xb, unsigned short* __restrict__ wx,
                           long n8x) {
    if (blockIdx.x < 2048) {
        long idx = (long)blockIdx.x * blockDim.x + threadIdx.x;
        long stride = (long)2048 * blockDim.x;
        for (long i = idx; i < n8x; i += stride) {
            const float4 a = ((const float4*)x)[2 * i];
            const float4 b = ((const float4*)x)[2 * i + 1];
            ushort8 s;
            s[0] = f2bf(a.x); s[1] = f2bf(a.y); s[2] = f2bf(a.z); s[3] = f2bf(a.w);
            s[4] = f2bf(b.x); s[5] = f2bf(b.y); s[6] = f2bf(b.z); s[7] = f2bf(b.w);
            ((ushort8*)xb)[i] = s;
        }
    } else {
        const int R0 = rn[0], R1 = rn[1], R2 = rn[2], R3 = rn[3];
        const long total = (long)NDIM * (KDIM / 8);
        long idx = (long)(blockIdx.x - 2048) * blockDim.x + threadIdx.x;
        long stride = (long)1024 * blockDim.x;
        for (long t = idx; t < total; t += stride) {
            const int kp = (int)(t & (KDIM / 8 - 1));
            const int n  = (int)(t >> 9);
            const int k0 = kp * 8;
            const int i  = k0 >> 5;
            const int kk0 = k0 & 31;
            const int it = i >> 1;
            const int h  = R3 + R2 * (n >> 5) + R1 * (it + 1) + R0 * ((i & 1) + 1);
            const int off = 32 - ((h << 2) & 31);
            const float* src = w + (long)n * REDIN + it * 32;
            ushort8 s;
#pragma unroll
            for (int q = 0; q < 8; ++q)
                s[q] = f2bf(src[(kk0 + q + off) & 31]);
            ((ushort8*)wx)[t] = s;
        }
    }
}

// ======== main GEMM: 256x256, BK=64, 2-buf ring, 4 phases/group, 1 bar/phase (R11, verified) ========
// 8 waves 2Mx4N, per-wave 128x64. LDS: A[2buf][2half][128][64]bf16 64KB + B same.
// Bank swizzle (proven 0-conflict): phys 16B slot = logical ^ (row&7);
// linear gload dest + inverse-swizzled global source + swizzled ds_read.
// Group u (tile u from buf u&1), 4 phases, ONE barrier per phase:
//   P1: read A(mh0)x8 + B(nh0)x4; stage A(u+1) h0+h1; lgkm(4); BAR; lgkm(0); MFMA(0,0)
//   P2: read B(nh1)x4;                                      BAR; lgkm(0); MFMA(0,1)
//   P3: read A(mh1)x8;            stage B(u+2)h0;           BAR; lgkm(0); MFMA(1,1)
//   P4: stage B(u+2)h1; MFMA(1,0); vmcnt(4); BAR
// WAR audit:
//  * A(u+1) stage @P1(u) -> buf[(u+1)&1] (the OTHER buffer): last reads were P3(u-1),
//    drained at lgkm(0) before MFMA(1,1,u-1) < BAR(P4,u-1) < P1(u) stage. OK.
//  * B(u+2)h0 @P3 / h1 @P4 -> buf[u&1]: all B reads of buf[u&1] (nh0@P1, nh1@P2) drained
//    at their lgkm(0) before the preceding barriers; stage issue follows them. OK.
// RAW gate: vmcnt(4)@P4(u) leaves only B(u+2)'s 4 loads outstanding => A(u+1) (this
//  group P1) and B(u+1) (prev group P3/P4) landed before BAR. With 2 buffers and M-half
//  staging, depth 4 is the maximum legal depth (R12/R14/R16 post-mortems: deeper staging
//  either races on live rows or regresses from gate/register overhead). Tail drains vmcnt(0).

#define STAGE_H(MAT, T, HALF)                                               \
  {                                                                         \
    char* _d = (char*)lds##MAT + ((((T) & 1) * 2 + (HALF)) * 16384) + tid * 16; \
    const unsigned short* _s = src##MAT + (size_t)((HALF) * 128) * KDIM + (size_t)(T) * 64; \
    gload16(_s, _d);                                                        \
    gload16(_s + (size_t)64 * KDIM, _d + 8192);                             \
  }

#define READ_A(PA, MH)                                                      \
  _Pragma("unroll")                                                         \
  for (int _kk = 0; _kk < 2; ++_kk)                                         \
    _Pragma("unroll")                                                       \
    for (int _mf = 0; _mf < 4; ++_mf)                                       \
      a_[_kk][_mf] = *(const bf16x8*)((PA) + (MH) * 8192 + _mf * 2048 + (roff ^ (_kk << 6)));

#define READ_B(PB, NH)                                                      \
  _Pragma("unroll")                                                         \
  for (int _kk = 0; _kk < 2; ++_kk)                                         \
    _Pragma("unroll")                                                       \
    for (int _nf = 0; _nf < 2; ++_nf)                                       \
      b_##NH[_kk][_nf] = *(const bf16x8*)((PB) + (NH) * 4096 + _nf * 2048 + (roff ^ (_kk << 6)));

#define MFMA_Q(MH, NH)                                                      \
  __builtin_amdgcn_s_setprio(1);                                            \
  _Pragma("unroll")                                                         \
  for (int _kk = 0; _kk < 2; ++_kk)                                         \
    _Pragma("unroll")                                                       \
    for (int _mf = 0; _mf < 4; ++_mf)                                       \
      _Pragma("unroll")                                                     \
      for (int _nf = 0; _nf < 2; ++_nf)                                     \
        acc[(MH) * 4 + _mf][(NH) * 2 + _nf] = __builtin_amdgcn_mfma_f32_16x16x32_bf16( \
            a_[_kk][_mf], b_##NH[_kk][_nf], acc[(MH) * 4 + _mf][(NH) * 2 + _nf], 0, 0, 0); \
  __builtin_amdgcn_s_setprio(0);

#define SB __builtin_amdgcn_sched_barrier(0)
#define BAR __builtin_amdgcn_s_barrier()

#define GROUP(U, BUF, STG, VMSTR)                                           \
  {                                                                         \
    const char* paA = ldsAc + ((BUF) * 2 + wr) * 16384;                     \
    const char* pbB = ldsBc + ((BUF) * 2 + bh) * 16384 + bhw;               \
    /* P1 */                                                                \
    READ_A(paA, 0)                                                          \
    READ_B(pbB, 0)                                                          \
    if ((STG) >= 1) { STAGE_H(A, (U) + 1, 0); STAGE_H(A, (U) + 1, 1); }     \
    asm volatile("s_waitcnt lgkmcnt(4)" ::: "memory");                      \
    SB; BAR;                                                                \
    asm volatile("s_waitcnt lgkmcnt(0)" ::: "memory");                      \
    SB;                                                                     \
    MFMA_Q(0, 0)                                                            \
    SB;                                                                     \
    /* P2 */                                                                \
    READ_B(pbB, 1)                                                          \
    SB; BAR;                                                                \
    asm volatile("s_waitcnt lgkmcnt(0)" ::: "memory");                      \
    SB;                                                                     \
    MFMA_Q(0, 1)                                                            \
    SB;                                                                     \
    /* P3 */                                                                \
    READ_A(paA, 1)                                                          \
    if ((STG) >= 2) STAGE_H(B, (U) + 2, 0);                                 \
    SB; BAR;                                                                \
    asm volatile("s_waitcnt lgkmcnt(0)" ::: "memory");                      \
    SB;                                                                     \
    MFMA_Q(1, 1)                                                            \
    SB;                                                                     \
    /* P4 */                                                                \
    if ((STG) >= 2) STAGE_H(B, (U) + 2, 1);                                 \
    SB;                                                                     \
    MFMA_Q(1, 0)                                                            \
    asm volatile("s_waitcnt vmcnt(" VMSTR ")" ::: "memory");                \
    SB; BAR; SB;                                                            \
  }

__global__ __launch_bounds__(512, 2)
void gemm_bt256(const unsigned short* __restrict__ A,   // bf16 [M][K]
                const unsigned short* __restrict__ B,   // bf16 [N][K]
                const float* __restrict__ bias,
                float* __restrict__ out, int M)
{
    __shared__ __align__(16) unsigned short ldsA[2 * 2 * 8192];   // 64 KB
    __shared__ __align__(16) unsigned short ldsB[2 * 2 * 8192];   // 64 KB
    const char* ldsAc = (const char*)ldsA;
    const char* ldsBc = (const char*)ldsB;

    // XCD-aware bijective swizzle (nwg = 16*(M/256), divisible by 8)
    const int nwg = gridDim.x;
    const int bid = blockIdx.x;
    int swzb = bid;
    if ((nwg & 7) == 0) {
        const int cpx = nwg >> 3;
        swzb = (bid & 7) * cpx + (bid >> 3);
    }
    const int ntn = NDIM / 256;                 // 16
    const int n0 = (swzb % ntn) * 256;
    const int m0 = (swzb / ntn) * 256;

    const int tid  = threadIdx.x;
    const int lane = tid & 63;
    const int wid  = tid >> 6;
    const int wr   = wid >> 2;                  // A half (0..1)
    const int wc   = wid & 3;                   // 0..3
    const int bh   = wc >> 1;                   // B half
    const int bhw  = (wc & 1) * 8192;           // 64-row offset within B half (bytes)
    const int lrow = lane & 15;
    const int g    = lane >> 4;                 // k sub-group 0..3

    // frag read offset: row*128B + swizzled 16B slot
    const int roff = lrow * 128 + (((g ^ (lrow & 7)) & 7) << 4);

    // staging: linear LDS dest (tid*16B), inverse-swizzled global k source
    const int srow = tid >> 3;                  // 0..63
    const int sslot = (tid & 7) ^ (srow & 7);
    const unsigned short* srcA = A + (size_t)(m0 + srow) * KDIM + 8 * sslot;
    const unsigned short* srcB = B + (size_t)(n0 + srow) * KDIM + 8 * sslot;

    f32x4 acc[8][4];
#pragma unroll
    for (int m = 0; m < 8; ++m)
#pragma unroll
        for (int n = 0; n < 4; ++n)
            acc[m][n] = (f32x4)(0.0f);

    bf16x8 a_[2][4], b_0[2][2], b_1[2][2];

    // ---- prologue: tile0 (A0,A1,B0,B1) + tile1 (B0,B1) = 12 gloads ----
    STAGE_H(A, 0, 0);
    STAGE_H(A, 0, 1);
    STAGE_H(B, 0, 0);
    STAGE_H(B, 0, 1);
    STAGE_H(B, 1, 0);
    STAGE_H(B, 1, 1);
    asm volatile("s_waitcnt vmcnt(4)" ::: "memory");   // tile 0 landed; B(1) in flight
    SB; BAR; SB;

    // ---- main: groups 0..61 ----
    for (int u = 0; u < 62; u += 2) {
        GROUP(u,     0, 2, "4");
        GROUP(u + 1, 1, 2, "4");
    }
    // ---- tail ----
    GROUP(62, 0, 1, "0");   // stages A(63) only; gate drains everything
    GROUP(63, 1, 0, "0");   // compute-only

    // ---- epilogue ----
#pragma unroll
    for (int n = 0; n < 4; ++n) {
        const int col = n0 + wc * 64 + n * 16 + lrow;
        const float bv = bias[col];
#pragma unroll
        for (int m = 0; m < 8; ++m) {
            const size_t rbase = (size_t)(m0 + wr * 128 + m * 16 + (lane >> 4) * 4);
#pragma unroll
            for (int e = 0; e < 4; ++e)
                out[(rbase + e) * NDIM + col] = acc[m][n][e] + bv;
        }
    }
}

// ---------------- fallback (fused) for small ws ----------------
__global__ __launch_bounds__(256, 2)
void ssl_gemm_fused(const float* __restrict__ x, const float* __restrict__ w,
                    const float* __restrict__ bias, const int* __restrict__ rn,
                    float* __restrict__ out)
{
    __shared__ __align__(16) unsigned short As[128][40];
    __shared__ __align__(16) unsigned short Bs[128][40];

    const int R0 = rn[0], R1 = rn[1], R2 = rn[2], R3 = rn[3];
    const int tid = threadIdx.x;
    const int n0 = blockIdx.x * 128;
    const int m0 = blockIdx.y * 128;
    const int srow = tid >> 3;
    const int scol = (tid & 7) * 4;
    const int lane = tid & 63;
    const int wid  = tid >> 6;
    const int wr   = wid >> 1;
    const int wc   = wid & 1;
    const int lrow = lane & 15;
    const int lk   = (lane >> 4) * 8;

    f32x4 acc[4][4];
#pragma unroll
    for (int m = 0; m < 4; ++m)
#pragma unroll
        for (int n = 0; n < 4; ++n)
            acc[m][n] = (f32x4)(0.0f);

    for (int i = 0; i < KDIM / 32; ++i) {
        const int it   = i >> 1;
        const int k0   = i * 32;
#pragma unroll
        for (int p = 0; p < 4; ++p) {
            const int row = p * 32 + srow;
            const float4 v = *(const float4*)(x + (size_t)(m0 + row) * KDIM + k0 + scol);
            ushort4 s;
            s.x = f2bf(v.x); s.y = f2bf(v.y); s.z = f2bf(v.z); s.w = f2bf(v.w);
            *(ushort4*)&As[row][scol] = s;
        }
        const int hbase = R3 + R1 * (it + 1) + R0 * ((i & 1) + 1);
#pragma unroll
        for (int p = 0; p < 4; ++p) {
            const int nl = p * 32 + srow;
            const int j  = (n0 + nl) >> 5;
            const int off = 32 - (((hbase + R2 * j) << 2) & 31);
            const float4 v = *(const float4*)(w + (size_t)(n0 + nl) * REDIN + it * 32 + scol);
            Bs[nl][(scol + 0 - off) & 31] = f2bf(v.x);
            Bs[nl][(scol + 1 - off) & 31] = f2bf(v.y);
            Bs[nl][(scol + 2 - off) & 31] = f2bf(v.z);
            Bs[nl][(scol + 3 - off) & 31] = f2bf(v.w);
        }
        __syncthreads();

        bf16x8 af[4], bfr[4];
#pragma unroll
        for (int m = 0; m < 4; ++m)
            af[m] = *(const bf16x8*)&As[wr * 64 + m * 16 + lrow][lk];
#pragma unroll
        for (int n = 0; n < 4; ++n)
            bfr[n] = *(const bf16x8*)&Bs[wc * 64 + n * 16 + lrow][lk];
#pragma unroll
        for (int m = 0; m < 4; ++m)
#pragma unroll
            for (int n = 0; n < 4; ++n)
                acc[m][n] = __builtin_amdgcn_mfma_f32_16x16x32_bf16(af[m], bfr[n], acc[m][n], 0, 0, 0);
        __syncthreads();
    }

#pragma unroll
    for (int n = 0; n < 4; ++n) {
        const int col = n0 + wc * 64 + n * 16 + lrow;
        const float bv = bias[col];
#pragma unroll
        for (int m = 0; m < 4; ++m) {
            const int rbase = m0 + wr * 64 + m * 16 + (lane >> 4) * 4;
#pragma unroll
            for (int e = 0; e < 4; ++e)
                out[(size_t)(rbase + e) * NDIM + col] = acc[m][n][e] + bv;
        }
    }
}

extern "C" void kernel_launch(void* const* d_in, const int* in_sizes, int n_in,
                              void* d_out, int out_size, void* d_ws, size_t ws_size,
                              hipStream_t stream) {
    const float* x    = (const float*)d_in[0];
    const float* wgt  = (const float*)d_in[1];
    const float* bias = (const float*)d_in[2];
    const int*   rn   = (const int*)d_in[3];
    float* out = (float*)d_out;

    const int M = in_sizes[0] / KDIM;                       // 8192
    const size_t need = ((size_t)M * KDIM + (size_t)NDIM * KDIM) * sizeof(unsigned short);

    if (ws_size >= need && (M % 256) == 0) {
        unsigned short* xb = (unsigned short*)d_ws;
        unsigned short* wx = xb + (size_t)M * KDIM;

        prep_fused<<<3072, 256, 0, stream>>>(x, wgt, rn, xb, wx, (long)M * KDIM / 8);

        const int nwg = (NDIM / 256) * (M / 256);           // 512
        gemm_bt256<<<nwg, 512, 0, stream>>>(xb, wx, bias, out, M);
    } else {
        dim3 grid(NDIM / 128, M / 128);
        ssl_gemm_fused<<<grid, dim3(256), 0, stream>>>(x, wgt, bias, rn, out);
    }
}

// Round 18
// 265.433 us; speedup vs baseline: 1.0910x; 1.0241x over previous
//
#include <hip/hip_runtime.h>

typedef __bf16 bf16x8 __attribute__((ext_vector_type(8)));
typedef float  f32x4  __attribute__((ext_vector_type(4)));
typedef unsigned short ushort8 __attribute__((ext_vector_type(8)));

#define KDIM  4096
#define NDIM  4096
#define REDIN 2048

static __device__ __forceinline__ unsigned short f2bf(float f) {
    return __builtin_bit_cast(unsigned short, (__bf16)f);
}

typedef __attribute__((address_space(3))) void       lds_void;
typedef const __attribute__((address_space(1))) void gbl_cvoid;

static __device__ __forceinline__ void gload16(const void* g, void* l) {
    __builtin_amdgcn_global_load_lds((gbl_cvoid*)g, (lds_void*)l, 16, 0, 0);
}

// ---------------- fused prep: blocks [0,2048) convert x; [2048,3072) expand w ----------------
__global__ void prep_fused(const float* __restrict__ x, const float* __restrict__ w,
                           const int* __restrict__ rn,
                           unsigned short* __restrict__ xb, unsigned short* __restrict__ wx,
                           long n8x) {
    if (blockIdx.x < 2048) {
        long idx = (long)blockIdx.x * blockDim.x + threadIdx.x;
        long stride = (long)2048 * blockDim.x;
        for (long i = idx; i < n8x; i += stride) {
            const float4 a = ((const float4*)x)[2 * i];
            const float4 b = ((const float4*)x)[2 * i + 1];
            ushort8 s;
            s[0] = f2bf(a.x); s[1] = f2bf(a.y); s[2] = f2bf(a.z); s[3] = f2bf(a.w);
            s[4] = f2bf(b.x); s[5] = f2bf(b.y); s[6] = f2bf(b.z); s[7] = f2bf(b.w);
            ((ushort8*)xb)[i] = s;
        }
    } else {
        const int R0 = rn[0], R1 = rn[1], R2 = rn[2], R3 = rn[3];
        const long total = (long)NDIM * (KDIM / 8);
        long idx = (long)(blockIdx.x - 2048) * blockDim.x + threadIdx.x;
        long stride = (long)1024 * blockDim.x;
        for (long t = idx; t < total; t += stride) {
            const int kp = (int)(t & (KDIM / 8 - 1));
            const int n  = (int)(t >> 9);
            const int k0 = kp * 8;
            const int i  = k0 >> 5;
            const int kk0 = k0 & 31;
            const int it = i >> 1;
            const int h  = R3 + R2 * (n >> 5) + R1 * (it + 1) + R0 * ((i & 1) + 1);
            const int off = 32 - ((h << 2) & 31);
            const float* src = w + (long)n * REDIN + it * 32;
            ushort8 s;
#pragma unroll
            for (int q = 0; q < 8; ++q)
                s[q] = f2bf(src[(kk0 + q + off) & 31]);
            ((ushort8*)wx)[t] = s;
        }
    }
}

// ======== main GEMM: 256x256, BK=64, 2-buf ring, 4 phases/group, 1 bar/phase (R11 K-loop) ========
// K-loop byte-identical to the verified R11 (246us GEMM, MfmaUtil 50.5, 0 conflicts).
// NEW: LDS-coalesced epilogue — C routed through (dead) ldsA so stores are full 128B lines.
// Group u (tile u from buf u&1), 4 phases, ONE barrier per phase:
//   P1: read A(mh0)x8 + B(nh0)x4; stage A(u+1) h0+h1; lgkm(4); BAR; lgkm(0); MFMA(0,0)
//   P2: read B(nh1)x4;                                      BAR; lgkm(0); MFMA(0,1)
//   P3: read A(mh1)x8;            stage B(u+2)h0;           BAR; lgkm(0); MFMA(1,1)
//   P4: stage B(u+2)h1; MFMA(1,0); vmcnt(4); BAR
// WAR/RAW audit unchanged from R11 (see R15 comments). Depth-4 gate is the max legal depth
// for 2-buf M-half staging (R12/R14/R16 post-mortems).

#define STAGE_H(MAT, T, HALF)                                               \
  {                                                                         \
    char* _d = (char*)lds##MAT + ((((T) & 1) * 2 + (HALF)) * 16384) + tid * 16; \
    const unsigned short* _s = src##MAT + (size_t)((HALF) * 128) * KDIM + (size_t)(T) * 64; \
    gload16(_s, _d);                                                        \
    gload16(_s + (size_t)64 * KDIM, _d + 8192);                             \
  }

#define READ_A(PA, MH)                                                      \
  _Pragma("unroll")                                                         \
  for (int _kk = 0; _kk < 2; ++_kk)                                         \
    _Pragma("unroll")                                                       \
    for (int _mf = 0; _mf < 4; ++_mf)                                       \
      a_[_kk][_mf] = *(const bf16x8*)((PA) + (MH) * 8192 + _mf * 2048 + (roff ^ (_kk << 6)));

#define READ_B(PB, NH)                                                      \
  _Pragma("unroll")                                                         \
  for (int _kk = 0; _kk < 2; ++_kk)                                         \
    _Pragma("unroll")                                                       \
    for (int _nf = 0; _nf < 2; ++_nf)                                       \
      b_##NH[_kk][_nf] = *(const bf16x8*)((PB) + (NH) * 4096 + _nf * 2048 + (roff ^ (_kk << 6)));

#define MFMA_Q(MH, NH)                                                      \
  __builtin_amdgcn_s_setprio(1);                                            \
  _Pragma("unroll")                                                         \
  for (int _kk = 0; _kk < 2; ++_kk)                                         \
    _Pragma("unroll")                                                       \
    for (int _mf = 0; _mf < 4; ++_mf)                                       \
      _Pragma("unroll")                                                     \
      for (int _nf = 0; _nf < 2; ++_nf)                                     \
        acc[(MH) * 4 + _mf][(NH) * 2 + _nf] = __builtin_amdgcn_mfma_f32_16x16x32_bf16( \
            a_[_kk][_mf], b_##NH[_kk][_nf], acc[(MH) * 4 + _mf][(NH) * 2 + _nf], 0, 0, 0); \
  __builtin_amdgcn_s_setprio(0);

#define SB __builtin_amdgcn_sched_barrier(0)
#define BAR __builtin_amdgcn_s_barrier()

#define GROUP(U, BUF, STG, VMSTR)                                           \
  {                                                                         \
    const char* paA = ldsAc + ((BUF) * 2 + wr) * 16384;                     \
    const char* pbB = ldsBc + ((BUF) * 2 + bh) * 16384 + bhw;               \
    /* P1 */                                                                \
    READ_A(paA, 0)                                                          \
    READ_B(pbB, 0)                                                          \
    if ((STG) >= 1) { STAGE_H(A, (U) + 1, 0); STAGE_H(A, (U) + 1, 1); }     \
    asm volatile("s_waitcnt lgkmcnt(4)" ::: "memory");                      \
    SB; BAR;                                                                \
    asm volatile("s_waitcnt lgkmcnt(0)" ::: "memory");                      \
    SB;                                                                     \
    MFMA_Q(0, 0)                                                            \
    SB;                                                                     \
    /* P2 */                                                                \
    READ_B(pbB, 1)                                                          \
    SB; BAR;                                                                \
    asm volatile("s_waitcnt lgkmcnt(0)" ::: "memory");                      \
    SB;                                                                     \
    MFMA_Q(0, 1)                                                            \
    SB;                                                                     \
    /* P3 */                                                                \
    READ_A(paA, 1)                                                          \
    if ((STG) >= 2) STAGE_H(B, (U) + 2, 0);                                 \
    SB; BAR;                                                                \
    asm volatile("s_waitcnt lgkmcnt(0)" ::: "memory");                      \
    SB;                                                                     \
    MFMA_Q(1, 1)                                                            \
    SB;                                                                     \
    /* P4 */                                                                \
    if ((STG) >= 2) STAGE_H(B, (U) + 2, 1);                                 \
    SB;                                                                     \
    MFMA_Q(1, 0)                                                            \
    asm volatile("s_waitcnt vmcnt(" VMSTR ")" ::: "memory");                \
    SB; BAR; SB;                                                            \
  }

__global__ __launch_bounds__(512, 2)
void gemm_bt256(const unsigned short* __restrict__ A,   // bf16 [M][K]
                const unsigned short* __restrict__ B,   // bf16 [N][K]
                const float* __restrict__ bias,
                float* __restrict__ out, int M)
{
    __shared__ __align__(16) unsigned short ldsA[2 * 2 * 8192];   // 64 KB
    __shared__ __align__(16) unsigned short ldsB[2 * 2 * 8192];   // 64 KB
    const char* ldsAc = (const char*)ldsA;
    const char* ldsBc = (const char*)ldsB;

    // XCD-aware bijective swizzle (nwg = 16*(M/256), divisible by 8)
    const int nwg = gridDim.x;
    const int bid = blockIdx.x;
    int swzb = bid;
    if ((nwg & 7) == 0) {
        const int cpx = nwg >> 3;
        swzb = (bid & 7) * cpx + (bid >> 3);
    }
    const int ntn = NDIM / 256;                 // 16
    const int n0 = (swzb % ntn) * 256;
    const int m0 = (swzb / ntn) * 256;

    const int tid  = threadIdx.x;
    const int lane = tid & 63;
    const int wid  = tid >> 6;
    const int wr   = wid >> 2;                  // A half (0..1)
    const int wc   = wid & 3;                   // 0..3
    const int bh   = wc >> 1;                   // B half
    const int bhw  = (wc & 1) * 8192;           // 64-row offset within B half (bytes)
    const int lrow = lane & 15;
    const int g    = lane >> 4;                 // k sub-group 0..3

    // frag read offset: row*128B + swizzled 16B slot
    const int roff = lrow * 128 + (((g ^ (lrow & 7)) & 7) << 4);

    // staging: linear LDS dest (tid*16B), inverse-swizzled global k source
    const int srow = tid >> 3;                  // 0..63
    const int sslot = (tid & 7) ^ (srow & 7);
    const unsigned short* srcA = A + (size_t)(m0 + srow) * KDIM + 8 * sslot;
    const unsigned short* srcB = B + (size_t)(n0 + srow) * KDIM + 8 * sslot;

    f32x4 acc[8][4];
#pragma unroll
    for (int m = 0; m < 8; ++m)
#pragma unroll
        for (int n = 0; n < 4; ++n)
            acc[m][n] = (f32x4)(0.0f);

    bf16x8 a_[2][4], b_0[2][2], b_1[2][2];

    // ---- prologue: tile0 (A0,A1,B0,B1) + tile1 (B0,B1) = 12 gloads ----
    STAGE_H(A, 0, 0);
    STAGE_H(A, 0, 1);
    STAGE_H(B, 0, 0);
    STAGE_H(B, 0, 1);
    STAGE_H(B, 1, 0);
    STAGE_H(B, 1, 1);
    asm volatile("s_waitcnt vmcnt(4)" ::: "memory");   // tile 0 landed; B(1) in flight
    SB; BAR; SB;

    // ---- main: groups 0..61 ----
    for (int u = 0; u < 62; u += 2) {
        GROUP(u,     0, 2, "4");
        GROUP(u + 1, 1, 2, "4");
    }
    // ---- tail ----
    GROUP(62, 0, 1, "0");   // stages A(63) only; gate drains everything
    GROUP(63, 1, 0, "0");   // compute-only

    // ---- epilogue: LDS-coalesced C write (ldsA is dead after the final BAR) ----
    // Write acc (MFMA layout) into ldsA as a [64 rows][256 cols] f32 tile per iteration
    // (rows = {mi in 0..1} x {band wr} x 16), then read back linearly: 64 consecutive
    // threads cover one full 1KB output row -> global_store_dwordx4, perfect 128B lines.
    // Bijective LDS addressing: (wr,wc) wave-unique, (g,lrow) lane-unique, (mi,n,e) loop-unique.
    {
        float* lf = (float*)ldsA;
        float bv[4];
#pragma unroll
        for (int n = 0; n < 4; ++n)
            bv[n] = bias[n0 + wc * 64 + n * 16 + lrow];

#pragma unroll
        for (int mb = 0; mb < 4; ++mb) {        // m pairs {0,1},{2,3},{4,5},{6,7}
            __syncthreads();                    // prior iteration's reads (or K-loop) done
#pragma unroll
            for (int mi = 0; mi < 2; ++mi) {
                const int m = mb * 2 + mi;
#pragma unroll
                for (int n = 0; n < 4; ++n)
#pragma unroll
                    for (int e = 0; e < 4; ++e)
                        lf[((mi * 2 + wr) * 16 + g * 4 + e) * 256 + wc * 64 + n * 16 + lrow]
                            = acc[m][n][e] + bv[n];
            }
            __syncthreads();
#pragma unroll
            for (int i = 0; i < 8; ++i) {
                const int f   = tid + i * 512;          // 0..4095 (float4 index)
                const int lr  = f >> 6;                 // 0..63 local row
                const int mi  = lr >> 5;
                const int band = (lr >> 4) & 1;
                const int r16 = lr & 15;
                const size_t grow = (size_t)(m0 + band * 128 + (mb * 2 + mi) * 16 + r16);
                const int    gc4  = (n0 >> 2) + (f & 63);
                ((float4*)out)[grow * (NDIM / 4) + gc4] = ((const float4*)lf)[f];
            }
        }
    }
}

// ---------------- fallback (fused) for small ws ----------------
__global__ __launch_bounds__(256, 2)
void ssl_gemm_fused(const float* __restrict__ x, const float* __restrict__ w,
                    const float* __restrict__ bias, const int* __restrict__ rn,
                    float* __restrict__ out)
{
    __shared__ __align__(16) unsigned short As[128][40];
    __shared__ __align__(16) unsigned short Bs[128][40];

    const int R0 = rn[0], R1 = rn[1], R2 = rn[2], R3 = rn[3];
    const int tid = threadIdx.x;
    const int n0 = blockIdx.x * 128;
    const int m0 = blockIdx.y * 128;
    const int srow = tid >> 3;
    const int scol = (tid & 7) * 4;
    const int lane = tid & 63;
    const int wid  = tid >> 6;
    const int wr   = wid >> 1;
    const int wc   = wid & 1;
    const int lrow = lane & 15;
    const int lk   = (lane >> 4) * 8;

    f32x4 acc[4][4];
#pragma unroll
    for (int m = 0; m < 4; ++m)
#pragma unroll
        for (int n = 0; n < 4; ++n)
            acc[m][n] = (f32x4)(0.0f);

    for (int i = 0; i < KDIM / 32; ++i) {
        const int it   = i >> 1;
        const int k0   = i * 32;
#pragma unroll
        for (int p = 0; p < 4; ++p) {
            const int row = p * 32 + srow;
            const float4 v = *(const float4*)(x + (size_t)(m0 + row) * KDIM + k0 + scol);
            ushort4 s;
            s.x = f2bf(v.x); s.y = f2bf(v.y); s.z = f2bf(v.z); s.w = f2bf(v.w);
            *(ushort4*)&As[row][scol] = s;
        }
        const int hbase = R3 + R1 * (it + 1) + R0 * ((i & 1) + 1);
#pragma unroll
        for (int p = 0; p < 4; ++p) {
            const int nl = p * 32 + srow;
            const int j  = (n0 + nl) >> 5;
            const int off = 32 - (((hbase + R2 * j) << 2) & 31);
            const float4 v = *(const float4*)(w + (size_t)(n0 + nl) * REDIN + it * 32 + scol);
            Bs[nl][(scol + 0 - off) & 31] = f2bf(v.x);
            Bs[nl][(scol + 1 - off) & 31] = f2bf(v.y);
            Bs[nl][(scol + 2 - off) & 31] = f2bf(v.z);
            Bs[nl][(scol + 3 - off) & 31] = f2bf(v.w);
        }
        __syncthreads();

        bf16x8 af[4], bfr[4];
#pragma unroll
        for (int m = 0; m < 4; ++m)
            af[m] = *(const bf16x8*)&As[wr * 64 + m * 16 + lrow][lk];
#pragma unroll
        for (int n = 0; n < 4; ++n)
            bfr[n] = *(const bf16x8*)&Bs[wc * 64 + n * 16 + lrow][lk];
#pragma unroll
        for (int m = 0; m < 4; ++m)
#pragma unroll
            for (int n = 0; n < 4; ++n)
                acc[m][n] = __builtin_amdgcn_mfma_f32_16x16x32_bf16(af[m], bfr[n], acc[m][n], 0, 0, 0);
        __syncthreads();
    }

#pragma unroll
    for (int n = 0; n < 4; ++n) {
        const int col = n0 + wc * 64 + n * 16 + lrow;
        const float bv = bias[col];
#pragma unroll
        for (int m = 0; m < 4; ++m) {
            const int rbase = m0 + wr * 64 + m * 16 + (lane >> 4) * 4;
#pragma unroll
            for (int e = 0; e < 4; ++e)
                out[(size_t)(rbase + e) * NDIM + col] = acc[m][n][e] + bv;
        }
    }
}

extern "C" void kernel_launch(void* const* d_in, const int* in_sizes, int n_in,
                              void* d_out, int out_size, void* d_ws, size_t ws_size,
                              hipStream_t stream) {
    const float* x    = (const float*)d_in[0];
    const float* wgt  = (const float*)d_in[1];
    const float* bias = (const float*)d_in[2];
    const int*   rn   = (const int*)d_in[3];
    float* out = (float*)d_out;

    const int M = in_sizes[0] / KDIM;                       // 8192
    const size_t need = ((size_t)M * KDIM + (size_t)NDIM * KDIM) * sizeof(unsigned short);

    if (ws_size >= need && (M % 256) == 0) {
        unsigned short* xb = (unsigned short*)d_ws;
        unsigned short* wx = xb + (size_t)M * KDIM;

        prep_fused<<<3072, 256, 0, stream>>>(x, wgt, rn, xb, wx, (long)M * KDIM / 8);

        const int nwg = (NDIM / 256) * (M / 256);           // 512
        gemm_bt256<<<nwg, 512, 0, stream>>>(xb, wx, bias, out, M);
    } else {
        dim3 grid(NDIM / 128, M / 128);
        ssl_gemm_fused<<<grid, dim3(256), 0, stream>>>(x, wgt, bias, rn, out);
    }
}